// Round 5
// baseline (560.322 us; speedup 1.0000x reference)
//
#include <hip/hip_runtime.h>
#include <hip/hip_bf16.h>

#define N_PTS 131072
#define CIN   32
#define COUT  32
#define KNB   27
#define NS    3

typedef __bf16 bf16x8 __attribute__((ext_vector_type(8)));
typedef float  f32x4  __attribute__((ext_vector_type(4)));

// Static device scratch (rewritten deterministically every call).
__device__ __attribute__((aligned(256))) __bf16 g_xT[(size_t)N_PTS * 64];   // [n][b][c] bf16
__device__ __attribute__((aligned(256))) __bf16 g_wp[NS * COUT * 864];      // [s][o][kc*32+c] bf16

// ---------------- pack x: (B,CIN,N) f32 -> (N, B, CIN) bf16 ----------------
__global__ void pack_x(const float* __restrict__ x) {
  int n = blockIdx.x * 256 + threadIdx.x;
  uint u[32];
#pragma unroll
  for (int b = 0; b < 2; ++b)
#pragma unroll
    for (int c = 0; c < 32; c += 2) {
      float f0 = x[(size_t)(b * 32 + c) * N_PTS + n];
      float f1 = x[(size_t)(b * 32 + c + 1) * N_PTS + n];
      union { __bf16 h[2]; uint w; } cv;
      cv.h[0] = (__bf16)f0; cv.h[1] = (__bf16)f1;
      u[b * 16 + c / 2] = cv.w;
    }
  uint4* dst = reinterpret_cast<uint4*>(&g_xT[(size_t)n * 64]);
#pragma unroll
  for (int i = 0; i < 8; ++i)
    dst[i] = make_uint4(u[4 * i], u[4 * i + 1], u[4 * i + 2], u[4 * i + 3]);
}

// ---------------- pack w: (CIN,S,COUT,27) f32 -> [s][o][kc*32+c] bf16 ------
__global__ void pack_w(const float* __restrict__ w) {
  int e = blockIdx.x * 256 + threadIdx.x;   // 3*32*864 = 82944 = 324*256
  int c  = e & 31;
  int kc = (e >> 5) % 27;
  int so = e / 864;           // s*32+o
  int o  = so & 31;
  int s  = so >> 5;
  g_wp[e] = (__bf16)w[((size_t)(c * NS + s) * COUT + o) * KNB + kc];
}

// ---------------- main GEMM: per block 64 points, all 32 outs --------------
// R1 structure (proven 90 us), occupancy raised 4 -> 7 blocks/CU.
// LDS 22.6 KB * 7 = 158.6 KB <= 160 KiB; VGPR 60 <= 512/7 = 73.
__global__ __launch_bounds__(256, 7) void aprconv(
    const int* __restrict__ nbr, const int* __restrict__ levels,
    const int* __restrict__ deltas, const float* __restrict__ bias,
    float* __restrict__ out) {

  __shared__ int   s_idx[KNB * 64];          // [kc][p]
  __shared__ int   s_lv[64];
  __shared__ float s_bias[COUT];
  __shared__ __attribute__((aligned(16))) __bf16 s_w[2][96 * 40];  // 96 rows (s*32+o), 80B padded stride

  const int tid = threadIdx.x;
  const int n0  = blockIdx.x * 64;
  const int wv  = tid >> 6;
  const int l15 = tid & 15;
  const int lg  = (tid & 63) >> 4;

  // stage neighbor indices (transposed: kc-major) + levels + bias
  for (int j = tid; j < 64 * KNB; j += 256) {
    int p = j / KNB, kc = j - p * KNB;
    s_idx[kc * 64 + p] = nbr[(size_t)(n0 + p) * KNB + kc];
  }
  if (tid < 64) s_lv[tid]  = levels[n0 + tid];
  if (tid < COUT) s_bias[tid] = bias[tid];

  // stage W chunk kc=0 into buffer 0 (384 x 16B chunks; 80B padded rows)
  {
    const char* wp = (const char*)g_wp;
    char* dst = (char*)&s_w[0][0];
    { int r = tid >> 2, seg = tid & 3;
      *(uint4*)(dst + r * 80 + seg * 16) = *(const uint4*)(wp + r * 1728 + seg * 16); }
    if (tid < 128) { int q = tid + 256; int r = q >> 2, seg = q & 3;
      *(uint4*)(dst + r * 80 + seg * 16) = *(const uint4*)(wp + r * 1728 + seg * 16); }
  }
  __syncthreads();

  const int d0 = deltas[0], d1 = deltas[1];

  f32x4 acc[2][3][2];
#pragma unroll
  for (int b = 0; b < 2; ++b)
#pragma unroll
    for (int s = 0; s < 3; ++s)
#pragma unroll
      for (int ot = 0; ot < 2; ++ot)
        acc[b][s][ot] = (f32x4){0.f, 0.f, 0.f, 0.f};

  const char* xbase = (const char*)g_xT;
  bf16x8 xf0, xf1;
  {
    int idv = s_idx[wv * 16 + l15];
    xf0 = *(const bf16x8*)(xbase + (size_t)idv * 128 + lg * 16);
    xf1 = *(const bf16x8*)(xbase + (size_t)idv * 128 + 64 + lg * 16);
  }

  for (int kc = 0; kc < KNB; ++kc) {
    const int cur = kc & 1;
    // W fragments: row = s*32 + ot*16 + (lane&15), 16B at (lane>>4)*16
    bf16x8 wf[3][2];
    const char* wb = (const char*)&s_w[cur][0];
#pragma unroll
    for (int s = 0; s < 3; ++s)
#pragma unroll
      for (int ot = 0; ot < 2; ++ot)
        wf[s][ot] = *(const bf16x8*)(wb + (s * 32 + ot * 16 + l15) * 80 + lg * 16);

    bf16x8 xn0, xn1; uint4 ws0, ws1;
    const bool last = (kc == KNB - 1);
    if (!last) {
      // prefetch next gather (x) and next W chunk (to regs)
      int idn = s_idx[(kc + 1) * 64 + wv * 16 + l15];
      xn0 = *(const bf16x8*)(xbase + (size_t)idn * 128 + lg * 16);
      xn1 = *(const bf16x8*)(xbase + (size_t)idn * 128 + 64 + lg * 16);
      const char* wp = (const char*)g_wp;
      { int r = tid >> 2, seg = tid & 3;
        ws0 = *(const uint4*)(wp + r * 1728 + (kc + 1) * 64 + seg * 16); }
      if (tid < 128) { int q = tid + 256; int r = q >> 2, seg = q & 3;
        ws1 = *(const uint4*)(wp + r * 1728 + (kc + 1) * 64 + seg * 16); }
    }

    // D[o][pt]: A = W (16 outs x 32 ch), B = gathered x (32 ch x 16 pts)
#pragma unroll
    for (int s = 0; s < 3; ++s)
#pragma unroll
      for (int ot = 0; ot < 2; ++ot) {
        acc[0][s][ot] = __builtin_amdgcn_mfma_f32_16x16x32_bf16(wf[s][ot], xf0, acc[0][s][ot], 0, 0, 0);
        acc[1][s][ot] = __builtin_amdgcn_mfma_f32_16x16x32_bf16(wf[s][ot], xf1, acc[1][s][ot], 0, 0, 0);
      }

    if (!last) {
      char* dst = (char*)&s_w[cur ^ 1][0];
      { int r = tid >> 2, seg = tid & 3;
        *(uint4*)(dst + r * 80 + seg * 16) = ws0; }
      if (tid < 128) { int q = tid + 256; int r = q >> 2, seg = q & 3;
        *(uint4*)(dst + r * 80 + seg * 16) = ws1; }
      xf0 = xn0; xf1 = xn1;
    }
    __syncthreads();
  }

  // epilogue: per-point s select + bias + store
  // D layout: col(point) = lane&15, row(out) = (lane>>4)*4 + reg
  const int p  = wv * 16 + l15;
  const int lv = s_lv[p];
  int e0 = lv + d0; e0 = e0 < 0 ? 0 : (e0 > 2 ? 2 : e0);
  int e1 = lv + d1; e1 = e1 < 0 ? 0 : (e1 > 2 ? 2 : e1);
  const int n = n0 + p;
#pragma unroll
  for (int b = 0; b < 2; ++b) {
    const int sb = b ? e1 : e0;
#pragma unroll
    for (int ot = 0; ot < 2; ++ot) {
      f32x4 a0 = acc[b][0][ot], a1 = acc[b][1][ot], a2 = acc[b][2][ot];
      f32x4 v;
#pragma unroll
      for (int r = 0; r < 4; ++r)
        v[r] = (sb == 0) ? a0[r] : ((sb == 1) ? a1[r] : a2[r]);
#pragma unroll
      for (int r = 0; r < 4; ++r) {
        int o = ot * 16 + lg * 4 + r;
        out[(size_t)(b * COUT + o) * N_PTS + n] = v[r] + s_bias[o];
      }
    }
  }
}

extern "C" void kernel_launch(void* const* d_in, const int* in_sizes, int n_in,
                              void* d_out, int out_size, void* d_ws, size_t ws_size,
                              hipStream_t stream) {
  const float* x    = (const float*)d_in[0];
  const float* w    = (const float*)d_in[1];
  const float* bias = (const float*)d_in[2];
  const int* nbr    = (const int*)d_in[3];
  const int* lv     = (const int*)d_in[4];
  const int* dlt    = (const int*)d_in[5];
  float* out        = (float*)d_out;

  hipLaunchKernelGGL(pack_x, dim3(N_PTS / 256), dim3(256), 0, stream, x);
  hipLaunchKernelGGL(pack_w, dim3((NS * COUT * 864) / 256), dim3(256), 0, stream, w);
  hipLaunchKernelGGL(aprconv, dim3(N_PTS / 64), dim3(256), 0, stream, nbr, lv, dlt, bias, out);
}

// Round 6
// 413.751 us; speedup vs baseline: 1.3543x; 1.3543x over previous
//
#include <hip/hip_runtime.h>
#include <hip/hip_bf16.h>

#define N_PTS 131072
#define CIN   32
#define COUT  32
#define KNB   27
#define NS    3

typedef __bf16 bf16x8 __attribute__((ext_vector_type(8)));
typedef float  f32x4  __attribute__((ext_vector_type(4)));

// Static device scratch (rewritten deterministically every call).
__device__ __attribute__((aligned(256))) __bf16 g_xT[(size_t)N_PTS * 64];   // [n][b][c] bf16
__device__ __attribute__((aligned(256))) __bf16 g_wp[NS * COUT * 864];      // [s][o][kc*32+c] bf16

// ---------------- pack x: (B,CIN,N) f32 -> (N, B, CIN) bf16 ----------------
__global__ void pack_x(const float* __restrict__ x) {
  int n = blockIdx.x * 256 + threadIdx.x;
  uint u[32];
#pragma unroll
  for (int b = 0; b < 2; ++b)
#pragma unroll
    for (int c = 0; c < 32; c += 2) {
      float f0 = x[(size_t)(b * 32 + c) * N_PTS + n];
      float f1 = x[(size_t)(b * 32 + c + 1) * N_PTS + n];
      union { __bf16 h[2]; uint w; } cv;
      cv.h[0] = (__bf16)f0; cv.h[1] = (__bf16)f1;
      u[b * 16 + c / 2] = cv.w;
    }
  uint4* dst = reinterpret_cast<uint4*>(&g_xT[(size_t)n * 64]);
#pragma unroll
  for (int i = 0; i < 8; ++i)
    dst[i] = make_uint4(u[4 * i], u[4 * i + 1], u[4 * i + 2], u[4 * i + 3]);
}

// ---------------- pack w: (CIN,S,COUT,27) f32 -> [s][o][kc*32+c] bf16 ------
__global__ void pack_w(const float* __restrict__ w) {
  int e = blockIdx.x * 256 + threadIdx.x;   // 3*32*864 = 82944 = 324*256
  int c  = e & 31;
  int kc = (e >> 5) % 27;
  int so = e / 864;           // s*32+o
  int o  = so & 31;
  int s  = so >> 5;
  g_wp[e] = (__bf16)w[((size_t)(c * NS + s) * COUT + o) * KNB + kc];
}

// ---------------- main GEMM: per block 64 points, all 32 outs --------------
// R1 structure (proven 90 us), occupancy raised 4 -> 6 blocks/CU.
// LDS 23040 B * 6 = 138 KB <= 160 KiB; VGPR 60 <= 512/6 -> 80 cap (no spill).
__global__ __launch_bounds__(256, 6) void aprconv(
    const int* __restrict__ nbr, const int* __restrict__ levels,
    const int* __restrict__ deltas, const float* __restrict__ bias,
    float* __restrict__ out) {

  __shared__ int   s_idx[KNB * 64];          // [kc][p]
  __shared__ int   s_lv[64];
  __shared__ float s_bias[COUT];
  __shared__ __attribute__((aligned(16))) __bf16 s_w[2][96 * 40];  // 96 rows (s*32+o), 80B padded stride

  const int tid = threadIdx.x;
  const int n0  = blockIdx.x * 64;
  const int wv  = tid >> 6;
  const int l15 = tid & 15;
  const int lg  = (tid & 63) >> 4;

  // stage neighbor indices (transposed: kc-major) + levels + bias
  for (int j = tid; j < 64 * KNB; j += 256) {
    int p = j / KNB, kc = j - p * KNB;
    s_idx[kc * 64 + p] = nbr[(size_t)(n0 + p) * KNB + kc];
  }
  if (tid < 64) s_lv[tid]  = levels[n0 + tid];
  if (tid < COUT) s_bias[tid] = bias[tid];

  // stage W chunk kc=0 into buffer 0 (384 x 16B chunks; 80B padded rows)
  {
    const char* wp = (const char*)g_wp;
    char* dst = (char*)&s_w[0][0];
    { int r = tid >> 2, seg = tid & 3;
      *(uint4*)(dst + r * 80 + seg * 16) = *(const uint4*)(wp + r * 1728 + seg * 16); }
    if (tid < 128) { int q = tid + 256; int r = q >> 2, seg = q & 3;
      *(uint4*)(dst + r * 80 + seg * 16) = *(const uint4*)(wp + r * 1728 + seg * 16); }
  }
  __syncthreads();

  const int d0 = deltas[0], d1 = deltas[1];

  f32x4 acc[2][3][2];
#pragma unroll
  for (int b = 0; b < 2; ++b)
#pragma unroll
    for (int s = 0; s < 3; ++s)
#pragma unroll
      for (int ot = 0; ot < 2; ++ot)
        acc[b][s][ot] = (f32x4){0.f, 0.f, 0.f, 0.f};

  const char* xbase = (const char*)g_xT;
  bf16x8 xf0, xf1;
  {
    int idv = s_idx[wv * 16 + l15];
    xf0 = *(const bf16x8*)(xbase + (size_t)idv * 128 + lg * 16);
    xf1 = *(const bf16x8*)(xbase + (size_t)idv * 128 + 64 + lg * 16);
  }

  for (int kc = 0; kc < KNB; ++kc) {
    const int cur = kc & 1;
    // W fragments: row = s*32 + ot*16 + (lane&15), 16B at (lane>>4)*16
    bf16x8 wf[3][2];
    const char* wb = (const char*)&s_w[cur][0];
#pragma unroll
    for (int s = 0; s < 3; ++s)
#pragma unroll
      for (int ot = 0; ot < 2; ++ot)
        wf[s][ot] = *(const bf16x8*)(wb + (s * 32 + ot * 16 + l15) * 80 + lg * 16);

    bf16x8 xn0, xn1; uint4 ws0, ws1;
    const bool last = (kc == KNB - 1);
    if (!last) {
      // prefetch next gather (x) and next W chunk (to regs)
      int idn = s_idx[(kc + 1) * 64 + wv * 16 + l15];
      xn0 = *(const bf16x8*)(xbase + (size_t)idn * 128 + lg * 16);
      xn1 = *(const bf16x8*)(xbase + (size_t)idn * 128 + 64 + lg * 16);
      const char* wp = (const char*)g_wp;
      { int r = tid >> 2, seg = tid & 3;
        ws0 = *(const uint4*)(wp + r * 1728 + (kc + 1) * 64 + seg * 16); }
      if (tid < 128) { int q = tid + 256; int r = q >> 2, seg = q & 3;
        ws1 = *(const uint4*)(wp + r * 1728 + (kc + 1) * 64 + seg * 16); }
    }

    // D[o][pt]: A = W (16 outs x 32 ch), B = gathered x (32 ch x 16 pts)
#pragma unroll
    for (int s = 0; s < 3; ++s)
#pragma unroll
      for (int ot = 0; ot < 2; ++ot) {
        acc[0][s][ot] = __builtin_amdgcn_mfma_f32_16x16x32_bf16(wf[s][ot], xf0, acc[0][s][ot], 0, 0, 0);
        acc[1][s][ot] = __builtin_amdgcn_mfma_f32_16x16x32_bf16(wf[s][ot], xf1, acc[1][s][ot], 0, 0, 0);
      }

    if (!last) {
      char* dst = (char*)&s_w[cur ^ 1][0];
      { int r = tid >> 2, seg = tid & 3;
        *(uint4*)(dst + r * 80 + seg * 16) = ws0; }
      if (tid < 128) { int q = tid + 256; int r = q >> 2, seg = q & 3;
        *(uint4*)(dst + r * 80 + seg * 16) = ws1; }
      xf0 = xn0; xf1 = xn1;
    }
    __syncthreads();
  }

  // epilogue: per-point s select + bias + store
  // D layout: col(point) = lane&15, row(out) = (lane>>4)*4 + reg
  const int p  = wv * 16 + l15;
  const int lv = s_lv[p];
  int e0 = lv + d0; e0 = e0 < 0 ? 0 : (e0 > 2 ? 2 : e0);
  int e1 = lv + d1; e1 = e1 < 0 ? 0 : (e1 > 2 ? 2 : e1);
  const int n = n0 + p;
#pragma unroll
  for (int b = 0; b < 2; ++b) {
    const int sb = b ? e1 : e0;
#pragma unroll
    for (int ot = 0; ot < 2; ++ot) {
      f32x4 a0 = acc[b][0][ot], a1 = acc[b][1][ot], a2 = acc[b][2][ot];
      f32x4 v;
#pragma unroll
      for (int r = 0; r < 4; ++r)
        v[r] = (sb == 0) ? a0[r] : ((sb == 1) ? a1[r] : a2[r]);
#pragma unroll
      for (int r = 0; r < 4; ++r) {
        int o = ot * 16 + lg * 4 + r;
        out[(size_t)(b * COUT + o) * N_PTS + n] = v[r] + s_bias[o];
      }
    }
  }
}

extern "C" void kernel_launch(void* const* d_in, const int* in_sizes, int n_in,
                              void* d_out, int out_size, void* d_ws, size_t ws_size,
                              hipStream_t stream) {
  const float* x    = (const float*)d_in[0];
  const float* w    = (const float*)d_in[1];
  const float* bias = (const float*)d_in[2];
  const int* nbr    = (const int*)d_in[3];
  const int* lv     = (const int*)d_in[4];
  const int* dlt    = (const int*)d_in[5];
  float* out        = (float*)d_out;

  hipLaunchKernelGGL(pack_x, dim3(N_PTS / 256), dim3(256), 0, stream, x);
  hipLaunchKernelGGL(pack_w, dim3((NS * COUT * 864) / 256), dim3(256), 0, stream, w);
  hipLaunchKernelGGL(aprconv, dim3(N_PTS / 64), dim3(256), 0, stream, nbr, lv, dlt, bias, out);
}

// Round 7
// 95.765 us; speedup vs baseline: 5.8510x; 4.3205x over previous
//
#include <hip/hip_runtime.h>
#include <hip/hip_bf16.h>

#define N_PTS 131072
#define CIN   32
#define COUT  32
#define KNB   27
#define NS    3

typedef __bf16 bf16x8 __attribute__((ext_vector_type(8)));
typedef float  f32x4  __attribute__((ext_vector_type(4)));

// Static device scratch (rewritten deterministically every call).
__device__ __attribute__((aligned(256))) __bf16 g_xT[(size_t)N_PTS * 64];   // [n][b][c] bf16
__device__ __attribute__((aligned(256))) __bf16 g_wp[NS * COUT * 864];      // [s][o][kc*32+c] bf16

// ---- fused pack: blocks [0,512) pack x, blocks [512,836) pack w -----------
// pack x: (B,CIN,N) f32 -> (N, B, CIN) bf16 (128B per point, full line use)
// pack w: (CIN,S,COUT,27) f32 -> [s][o][kc*32+c] bf16
__global__ void pack_xw(const float* __restrict__ x, const float* __restrict__ w) {
  if (blockIdx.x < 512) {
    int n = blockIdx.x * 256 + threadIdx.x;
    uint u[32];
#pragma unroll
    for (int b = 0; b < 2; ++b)
#pragma unroll
      for (int c = 0; c < 32; c += 2) {
        float f0 = x[(size_t)(b * 32 + c) * N_PTS + n];
        float f1 = x[(size_t)(b * 32 + c + 1) * N_PTS + n];
        union { __bf16 h[2]; uint w; } cv;
        cv.h[0] = (__bf16)f0; cv.h[1] = (__bf16)f1;
        u[b * 16 + c / 2] = cv.w;
      }
    uint4* dst = reinterpret_cast<uint4*>(&g_xT[(size_t)n * 64]);
#pragma unroll
    for (int i = 0; i < 8; ++i)
      dst[i] = make_uint4(u[4 * i], u[4 * i + 1], u[4 * i + 2], u[4 * i + 3]);
  } else {
    int e = (blockIdx.x - 512) * 256 + threadIdx.x;   // 3*32*864 = 82944 = 324*256
    int c  = e & 31;
    int kc = (e >> 5) % 27;
    int so = e / 864;           // s*32+o
    int o  = so & 31;
    int s  = so >> 5;
    g_wp[e] = (__bf16)w[((size_t)(c * NS + s) * COUT + o) * KNB + kc];
  }
}

// ---------------- main GEMM: per block 64 points, all 32 outs --------------
// R1 structure, proven codegen: launch_bounds(256,4), VGPR=60, no spill.
// At the measured random-line fabric wall (~2.4 TB/s, 214 MB traffic).
__global__ __launch_bounds__(256, 4) void aprconv(
    const int* __restrict__ nbr, const int* __restrict__ levels,
    const int* __restrict__ deltas, const float* __restrict__ bias,
    float* __restrict__ out) {

  __shared__ int   s_idx[KNB * 64];          // [kc][p]
  __shared__ int   s_lv[64];
  __shared__ float s_bias[COUT];
  __shared__ __attribute__((aligned(16))) __bf16 s_w[2][96 * 40];  // 96 rows (s*32+o), 80B padded stride

  const int tid = threadIdx.x;
  const int n0  = blockIdx.x * 64;
  const int wv  = tid >> 6;
  const int l15 = tid & 15;
  const int lg  = (tid & 63) >> 4;

  // stage neighbor indices (transposed: kc-major) + levels + bias
  for (int j = tid; j < 64 * KNB; j += 256) {
    int p = j / KNB, kc = j - p * KNB;
    s_idx[kc * 64 + p] = nbr[(size_t)(n0 + p) * KNB + kc];
  }
  if (tid < 64) s_lv[tid]  = levels[n0 + tid];
  if (tid < COUT) s_bias[tid] = bias[tid];

  // stage W chunk kc=0 into buffer 0 (384 x 16B chunks; 80B padded rows)
  {
    const char* wp = (const char*)g_wp;
    char* dst = (char*)&s_w[0][0];
    { int r = tid >> 2, seg = tid & 3;
      *(uint4*)(dst + r * 80 + seg * 16) = *(const uint4*)(wp + r * 1728 + seg * 16); }
    if (tid < 128) { int q = tid + 256; int r = q >> 2, seg = q & 3;
      *(uint4*)(dst + r * 80 + seg * 16) = *(const uint4*)(wp + r * 1728 + seg * 16); }
  }
  __syncthreads();

  const int d0 = deltas[0], d1 = deltas[1];

  f32x4 acc[2][3][2];
#pragma unroll
  for (int b = 0; b < 2; ++b)
#pragma unroll
    for (int s = 0; s < 3; ++s)
#pragma unroll
      for (int ot = 0; ot < 2; ++ot)
        acc[b][s][ot] = (f32x4){0.f, 0.f, 0.f, 0.f};

  const char* xbase = (const char*)g_xT;
  bf16x8 xf0, xf1;
  {
    int idv = s_idx[wv * 16 + l15];
    xf0 = *(const bf16x8*)(xbase + (size_t)idv * 128 + lg * 16);
    xf1 = *(const bf16x8*)(xbase + (size_t)idv * 128 + 64 + lg * 16);
  }

  for (int kc = 0; kc < KNB; ++kc) {
    const int cur = kc & 1;
    // W fragments: row = s*32 + ot*16 + (lane&15), 16B at (lane>>4)*16
    bf16x8 wf[3][2];
    const char* wb = (const char*)&s_w[cur][0];
#pragma unroll
    for (int s = 0; s < 3; ++s)
#pragma unroll
      for (int ot = 0; ot < 2; ++ot)
        wf[s][ot] = *(const bf16x8*)(wb + (s * 32 + ot * 16 + l15) * 80 + lg * 16);

    bf16x8 xn0, xn1; uint4 ws0, ws1;
    const bool last = (kc == KNB - 1);
    if (!last) {
      // prefetch next gather (x) and next W chunk (to regs)
      int idn = s_idx[(kc + 1) * 64 + wv * 16 + l15];
      xn0 = *(const bf16x8*)(xbase + (size_t)idn * 128 + lg * 16);
      xn1 = *(const bf16x8*)(xbase + (size_t)idn * 128 + 64 + lg * 16);
      const char* wp = (const char*)g_wp;
      { int r = tid >> 2, seg = tid & 3;
        ws0 = *(const uint4*)(wp + r * 1728 + (kc + 1) * 64 + seg * 16); }
      if (tid < 128) { int q = tid + 256; int r = q >> 2, seg = q & 3;
        ws1 = *(const uint4*)(wp + r * 1728 + (kc + 1) * 64 + seg * 16); }
    }

    // D[o][pt]: A = W (16 outs x 32 ch), B = gathered x (32 ch x 16 pts)
#pragma unroll
    for (int s = 0; s < 3; ++s)
#pragma unroll
      for (int ot = 0; ot < 2; ++ot) {
        acc[0][s][ot] = __builtin_amdgcn_mfma_f32_16x16x32_bf16(wf[s][ot], xf0, acc[0][s][ot], 0, 0, 0);
        acc[1][s][ot] = __builtin_amdgcn_mfma_f32_16x16x32_bf16(wf[s][ot], xf1, acc[1][s][ot], 0, 0, 0);
      }

    if (!last) {
      char* dst = (char*)&s_w[cur ^ 1][0];
      { int r = tid >> 2, seg = tid & 3;
        *(uint4*)(dst + r * 80 + seg * 16) = ws0; }
      if (tid < 128) { int q = tid + 256; int r = q >> 2, seg = q & 3;
        *(uint4*)(dst + r * 80 + seg * 16) = ws1; }
      xf0 = xn0; xf1 = xn1;
    }
    __syncthreads();
  }

  // epilogue: per-point s select + bias + store
  // D layout: col(point) = lane&15, row(out) = (lane>>4)*4 + reg
  const int p  = wv * 16 + l15;
  const int lv = s_lv[p];
  int e0 = lv + d0; e0 = e0 < 0 ? 0 : (e0 > 2 ? 2 : e0);
  int e1 = lv + d1; e1 = e1 < 0 ? 0 : (e1 > 2 ? 2 : e1);
  const int n = n0 + p;
#pragma unroll
  for (int b = 0; b < 2; ++b) {
    const int sb = b ? e1 : e0;
#pragma unroll
    for (int ot = 0; ot < 2; ++ot) {
      f32x4 a0 = acc[b][0][ot], a1 = acc[b][1][ot], a2 = acc[b][2][ot];
      f32x4 v;
#pragma unroll
      for (int r = 0; r < 4; ++r)
        v[r] = (sb == 0) ? a0[r] : ((sb == 1) ? a1[r] : a2[r]);
#pragma unroll
      for (int r = 0; r < 4; ++r) {
        int o = ot * 16 + lg * 4 + r;
        out[(size_t)(b * COUT + o) * N_PTS + n] = v[r] + s_bias[o];
      }
    }
  }
}

extern "C" void kernel_launch(void* const* d_in, const int* in_sizes, int n_in,
                              void* d_out, int out_size, void* d_ws, size_t ws_size,
                              hipStream_t stream) {
  const float* x    = (const float*)d_in[0];
  const float* w    = (const float*)d_in[1];
  const float* bias = (const float*)d_in[2];
  const int* nbr    = (const int*)d_in[3];
  const int* lv     = (const int*)d_in[4];
  const int* dlt    = (const int*)d_in[5];
  float* out        = (float*)d_out;

  hipLaunchKernelGGL(pack_xw, dim3(512 + 324), dim3(256), 0, stream, x, w);
  hipLaunchKernelGGL(aprconv, dim3(N_PTS / 64), dim3(256), 0, stream, nbr, lv, dlt, bias, out);
}